// Round 16
// baseline (341.950 us; speedup 1.0000x reference)
//
#include <hip/hip_runtime.h>
#include <hip/hip_bf16.h>

#define T_STEPS 32
#define BATCH 256
#define EDIM 512
#define HDIM 512
#define G4 2048       // 4*H
#define VOCAB 3000
#define VPAD 3072

// fused-prep role ranges (blocks of 256 threads)
#define NB_CVTW   8192    // 2 * G4 * 512 / 256
#define NB_WOUT   12288   // VPAD * 1024 / 256
#define NB_XS     16384   // T * B * E / 256
#define NB_CARRY  512     // B * H / 256

typedef short bf16x8 __attribute__((ext_vector_type(8)));
typedef float f32x4 __attribute__((ext_vector_type(4)));

__device__ __forceinline__ unsigned short f2b(float f){
  union { float f; unsigned int u; } x; x.f = f;
  unsigned int u = x.u;
  unsigned int r = (u + 0x7fffu + ((u >> 16) & 1u)) >> 16;
  return (unsigned short)r;
}
__device__ __forceinline__ float b2f(unsigned short h){
  union { unsigned int u; float f; } x; x.u = ((unsigned int)h) << 16;
  return x.f;
}
__device__ __forceinline__ float sigm(float x){ return 1.0f / (1.0f + expf(-x)); }

__device__ __forceinline__ void gload_lds16(const unsigned short* g, unsigned short* l){
  __builtin_amdgcn_global_load_lds(
      (const __attribute__((address_space(1))) unsigned int*)g,
      (__attribute__((address_space(3))) unsigned int*)l, 16, 0, 0);
}

// ---------------- fused prep: all independent input->workspace transforms ----------------
__global__ __launch_bounds__(256) void k_prep(
    const float* __restrict__ wih, const float* __restrict__ whh,
    const float* __restrict__ wout,
    const float* __restrict__ img, const float* __restrict__ txt,
    const float* __restrict__ emb, const int* __restrict__ ans,
    const float* __restrict__ h0, const float* __restrict__ c0,
    const int* __restrict__ lengths,
    unsigned short* __restrict__ o_ih, unsigned short* __restrict__ o_hh,
    unsigned short* __restrict__ o_wo, unsigned short* __restrict__ xs,
    unsigned short* __restrict__ hx, float* __restrict__ cx,
    int* __restrict__ bs, int* __restrict__ roff, int* __restrict__ meta,
    int* __restrict__ rmap){
  int bid = blockIdx.x;
  if (bid < NB_CVTW){
    int i = bid * 256 + threadIdx.x;
    int n1 = G4 * EDIM;
    if (i < n1) o_ih[i] = f2b(wih[i]);
    else o_hh[i - n1] = f2b(whh[i - n1]);
    return;
  }
  bid -= NB_CVTW;
  if (bid < NB_WOUT){
    int i = bid * 256 + threadIdx.x;
    int r = i >> 10, c = i & 1023;
    o_wo[i] = (r < VOCAB) ? f2b(wout[r * 1024 + c]) : (unsigned short)0;
    return;
  }
  bid -= NB_WOUT;
  if (bid < NB_XS){
    int i = bid * 256 + threadIdx.x;
    int e = i & (EDIM - 1);
    int r = i >> 9;              // t*B + b
    int t = r >> 8, b = r & 255;
    float v;
    if (t == 0) v = (e < 256) ? img[b * 256 + e] : txt[b * 256 + (e - 256)];
    else { int tok = ans[b * T_STEPS + (t - 1)]; v = emb[(size_t)tok * EDIM + e]; }
    xs[i] = f2b(v);
    return;
  }
  bid -= NB_XS;
  if (bid < NB_CARRY){
    int i = bid * 256 + threadIdx.x;
    hx[i] = f2b(h0[i]); cx[i] = c0[i];
    return;
  }
  // ---- lens role: one block, 256 threads ----
  {
    __shared__ int s[T_STEPS];
    __shared__ int sroff[T_STEPS + 1];
    int t = threadIdx.x;
    if (t < T_STEPS){
      int c = 0;
      for (int i = 0; i < BATCH; i++) c += (lengths[i] > t) ? 1 : 0;
      s[t] = c; bs[t] = c;
    }
    __syncthreads();
    if (t == 0){
      int acc = 0;
      for (int u = 0; u < T_STEPS; u++){ sroff[u] = acc; roff[u] = acc; acc += s[u]; }
      sroff[T_STEPS] = acc;
      meta[0] = acc;
    }
    __syncthreads();
    int ntot = sroff[T_STEPS];
    for (int r = t; r < T_STEPS * BATCH; r += 256){
      int tt = r >> 8, b = r & 255;
      if (b < s[tt]) rmap[sroff[tt] + b] = r;
    }
    for (int r = ntot + t; r < T_STEPS * BATCH; r += 256) rmap[r] = -1;
  }
}

// ---------------- staged 128x128 GEMM core, BK=64, XOR-swizzled LDS ----------------
template<int K>
__device__ __forceinline__ void gemm_tile(const unsigned short* __restrict__ A,
                                          const unsigned short* __restrict__ B,
                                          int row0, int col0,
                                          unsigned short* As, unsigned short* Bs,
                                          f32x4 acc[4][4]){
  const int tid = threadIdx.x, w = tid >> 6, l = tid & 63;
  const int la = l & 15, lkq = l >> 4;
  const int sr = l >> 3;            // row within 8-row staging group
  const int ss = (l & 7) ^ sr;      // pre-swizzled source slot
  const int wr = (w >> 1) * 64, wc = (w & 1) * 64;
  const unsigned short* gA = A + (size_t)(row0 + w * 32 + sr) * K + ss * 8;
  const unsigned short* gB = B + (size_t)(col0 + w * 32 + sr) * K + ss * 8;
  unsigned short* lA = As + (w * 32) * 64;
  unsigned short* lB = Bs + (w * 32) * 64;
  for (int k0 = 0; k0 < K; k0 += 64){
#pragma unroll
    for (int i = 0; i < 4; i++){
      gload_lds16(gA + (size_t)i * 8 * K + k0, lA + i * 8 * 64);
      gload_lds16(gB + (size_t)i * 8 * K + k0, lB + i * 8 * 64);
    }
    __syncthreads();
#pragma unroll
    for (int kk = 0; kk < 2; kk++){
      bf16x8 a[4], b[4];
#pragma unroll
      for (int i = 0; i < 4; i++){
        int r = wr + i * 16 + la;
        a[i] = *(const bf16x8*)(As + r * 64 + (((kk * 4 + lkq) ^ (r & 7)) << 3));
      }
#pragma unroll
      for (int i = 0; i < 4; i++){
        int r = wc + i * 16 + la;
        b[i] = *(const bf16x8*)(Bs + r * 64 + (((kk * 4 + lkq) ^ (r & 7)) << 3));
      }
#pragma unroll
      for (int mi = 0; mi < 4; mi++)
#pragma unroll
        for (int ni = 0; ni < 4; ni++)
          acc[mi][ni] = __builtin_amdgcn_mfma_f32_16x16x32_bf16(a[mi], b[ni], acc[mi][ni], 0, 0, 0);
    }
    __syncthreads();
  }
}

// ---------------- GEMM 1: XW = xs @ W_ih^T + b_ih + b_hh (bf16 out) ----------------
__global__ __launch_bounds__(256) void k_gemm_xw(const unsigned short* __restrict__ A,
                                                 const unsigned short* __restrict__ W,
                                                 const float* __restrict__ bih,
                                                 const float* __restrict__ bhh,
                                                 unsigned short* __restrict__ C){
  __shared__ unsigned short As[128 * 64], Bs[128 * 64];
  int row0 = blockIdx.x * 128, col0 = blockIdx.y * 128;
  f32x4 acc[4][4] = {};
  gemm_tile<EDIM>(A, W, row0, col0, As, Bs, acc);
  int tid = threadIdx.x, w = tid >> 6, l = tid & 63;
  int la = l & 15, r4 = (l >> 4) * 4;
  int wr = (w >> 1) * 64, wc = (w & 1) * 64;
#pragma unroll
  for (int ni = 0; ni < 4; ni++){
    int col = col0 + wc + ni * 16 + la;
    float bias = bih[col] + bhh[col];
#pragma unroll
    for (int mi = 0; mi < 4; mi++)
#pragma unroll
      for (int j = 0; j < 4; j++){
        int row = row0 + wr + mi * 16 + r4 + j;
        C[(size_t)row * G4 + col] = f2b(acc[mi][ni][j] + bias);
      }
  }
}

// ---------------- fused recurrent step: 512 blocks (16 rows x 16 hcols), wave=gate ----
// b[16] Whh hoist (r7) + NEW: cell-phase operands (cprev, hm2, cm2) prefetched at
// kernel start — __syncthreads is a compiler memory fence, so without explicit
// prefetch these global loads sit exposed on the post-barrier critical path.
__global__ __launch_bounds__(256, 2) void k_lstm_step(
    const unsigned short* __restrict__ XWt,
    const unsigned short* __restrict__ Whh,
    const unsigned short* __restrict__ hin,
    unsigned short* __restrict__ hout,
    float* __restrict__ cxio,
    unsigned short* __restrict__ hs_t,
    unsigned short* __restrict__ cs_t,
    const unsigned short* __restrict__ hs_m2,
    const unsigned short* __restrict__ cs_m2,
    int do_res){
  __shared__ unsigned short hA[16 * 512];   // swizzled h tile
  __shared__ float gbuf[4][16][17];
  const int w = threadIdx.x >> 6, l = threadIdx.x & 63;
  const int la = l & 15, lkq = l >> 4;
  const int row0 = blockIdx.x * 16;
  const int hc0  = blockIdx.y * 16;
  // ---- prefetch cell-phase operands (consumed after the final barrier) ----
  const int cr = threadIdx.x >> 4, cc = threadIdx.x & 15;
  const size_t pcell = (size_t)(row0 + cr) * HDIM + hc0 + cc;
  float cprev = cxio[pcell];
  float hm2 = b2f(hs_m2[pcell]);
  float cm2 = b2f(cs_m2[pcell]);
  // stage h tile: wave w stages rows {w, 4+w, 8+w, 12+w}; source slot pre-swizzled
#pragma unroll
  for (int i = 0; i < 4; i++){
    int r = i * 4 + w;
    gload_lds16(hin + (size_t)(row0 + r) * HDIM + ((l ^ (r & 7)) << 3), hA + r * 512);
  }
  // hoist ALL 16 Whh B-fragments (independent, issued back-to-back)
  const unsigned short* Bp = Whh + (size_t)(w * HDIM + hc0 + la) * HDIM + lkq * 8;
  bf16x8 b[16];
#pragma unroll
  for (int kk = 0; kk < 16; kk++) b[kk] = *(const bf16x8*)(Bp + kk * 32);
  // hoist XW (consumed after MFMA loop)
  const int r4 = lkq * 4;
  float x[4];
#pragma unroll
  for (int j = 0; j < 4; j++)
    x[j] = b2f(XWt[(size_t)(row0 + r4 + j) * G4 + w * HDIM + hc0 + la]);
  __syncthreads();
  f32x4 acc = {};
#pragma unroll
  for (int kk = 0; kk < 16; kk++){
    bf16x8 a = *(const bf16x8*)(hA + la * 512 + (((kk * 4 + lkq) ^ (la & 7)) << 3));
    acc = __builtin_amdgcn_mfma_f32_16x16x32_bf16(a, b[kk], acc, 0, 0, 0);
  }
#pragma unroll
  for (int j = 0; j < 4; j++) gbuf[w][r4 + j][la] = acc[j] + x[j];
  __syncthreads();
  {
    float gi = gbuf[0][cr][cc], gf = gbuf[1][cr][cc], gg = gbuf[2][cr][cc], go = gbuf[3][cr][cc];
    float cy = sigm(gf) * cprev + sigm(gi) * tanhf(gg);
    float hy = sigm(go) * tanhf(cy);
    hs_t[pcell] = f2b(hy);
    cs_t[pcell] = f2b(cy);
    float hn = hy, cn = cy;
    if (do_res){ hn += hm2; cn += cm2; }
    hout[pcell] = f2b(hn);
    cxio[pcell] = cn;
  }
}

// ---------------- GEMM 2: packed output projection, A gathered via rmap ----------------
__global__ __launch_bounds__(256) void k_gemm_out(const unsigned short* __restrict__ hs,
                                                  const unsigned short* __restrict__ cs,
                                                  const unsigned short* __restrict__ Wo,
                                                  const float* __restrict__ bout,
                                                  const int* __restrict__ meta,
                                                  const int* __restrict__ rmap,
                                                  float* __restrict__ out){
  int ntot = meta[0];
  int row0 = blockIdx.x * 128, col0 = blockIdx.y * 128;
  if (row0 >= ntot) return;
  __shared__ unsigned short As[128 * 64], Bs[128 * 64];
  const int tid = threadIdx.x, w = tid >> 6, l = tid & 63;
  const int la = l & 15, lkq = l >> 4;
  const int sr = l >> 3, ss = (l & 7) ^ sr;
  const int wr = (w >> 1) * 64, wc = (w & 1) * 64;
  int srow[4];
#pragma unroll
  for (int i = 0; i < 4; i++){
    int rr = rmap[row0 + w * 32 + sr + i * 8];
    srow[i] = rr < 0 ? 0 : rr;
  }
  const unsigned short* gB = Wo + (size_t)(col0 + w * 32 + sr) * 1024 + ss * 8;
  unsigned short* lA = As + (w * 32) * 64;
  unsigned short* lB = Bs + (w * 32) * 64;
  f32x4 acc[4][4] = {};
  for (int k0 = 0; k0 < 1024; k0 += 64){
#pragma unroll
    for (int i = 0; i < 4; i++){
      const unsigned short* srcA = (k0 < 512)
          ? hs + (size_t)srow[i] * 512 + k0 + ss * 8
          : cs + (size_t)srow[i] * 512 + (k0 - 512) + ss * 8;
      gload_lds16(srcA, lA + i * 8 * 64);
      gload_lds16(gB + (size_t)i * 8 * 1024 + k0, lB + i * 8 * 64);
    }
    __syncthreads();
#pragma unroll
    for (int kk = 0; kk < 2; kk++){
      bf16x8 a[4], b[4];
#pragma unroll
      for (int i = 0; i < 4; i++){
        int r = wr + i * 16 + la;
        a[i] = *(const bf16x8*)(As + r * 64 + (((kk * 4 + lkq) ^ (r & 7)) << 3));
      }
#pragma unroll
      for (int i = 0; i < 4; i++){
        int r = wc + i * 16 + la;
        b[i] = *(const bf16x8*)(Bs + r * 64 + (((kk * 4 + lkq) ^ (r & 7)) << 3));
      }
#pragma unroll
      for (int mi = 0; mi < 4; mi++)
#pragma unroll
        for (int ni = 0; ni < 4; ni++)
          acc[mi][ni] = __builtin_amdgcn_mfma_f32_16x16x32_bf16(a[mi], b[ni], acc[mi][ni], 0, 0, 0);
    }
    __syncthreads();
  }
  int r4 = (l >> 4) * 4;
#pragma unroll
  for (int ni = 0; ni < 4; ni++){
    int col = col0 + wc + ni * 16 + la;
    if (col >= VOCAB) continue;
    float bias = bout[col];
#pragma unroll
    for (int mi = 0; mi < 4; mi++)
#pragma unroll
      for (int j = 0; j < 4; j++){
        int row = row0 + wr + mi * 16 + r4 + j;
        if (row < ntot) out[(size_t)row * VOCAB + col] = acc[mi][ni][j] + bias;
      }
  }
}

extern "C" void kernel_launch(void* const* d_in, const int* in_sizes, int n_in,
                              void* d_out, int out_size, void* d_ws, size_t ws_size,
                              hipStream_t stream){
  const float* img   = (const float*)d_in[0];
  const float* txt   = (const float*)d_in[1];
  const float* h0    = (const float*)d_in[2];
  const float* c0    = (const float*)d_in[3];
  const float* emb   = (const float*)d_in[4];
  const float* W_ih  = (const float*)d_in[5];
  const float* W_hh  = (const float*)d_in[6];
  const float* b_ih  = (const float*)d_in[7];
  const float* b_hh  = (const float*)d_in[8];
  const float* W_out = (const float*)d_in[9];
  const float* b_out = (const float*)d_in[10];
  const int* answer  = (const int*)d_in[11];
  const int* lengths = (const int*)d_in[12];
  float* out = (float*)d_out;

  char* ws = (char*)d_ws;
  size_t off = 0;
  auto alloc = [&](size_t bytes) -> void* {
    void* p = ws + off; off += (bytes + 255) & ~(size_t)255; return p;
  };
  unsigned short* Wih_b = (unsigned short*)alloc((size_t)G4 * EDIM * 2);
  unsigned short* Whh_b = (unsigned short*)alloc((size_t)G4 * HDIM * 2);
  unsigned short* Wo_b  = (unsigned short*)alloc((size_t)VPAD * 1024 * 2);
  unsigned short* xs    = (unsigned short*)alloc((size_t)T_STEPS * BATCH * EDIM * 2);
  unsigned short* XW    = (unsigned short*)alloc((size_t)T_STEPS * BATCH * G4 * 2);
  unsigned short* hs    = (unsigned short*)alloc((size_t)T_STEPS * BATCH * HDIM * 2);
  unsigned short* cs    = (unsigned short*)alloc((size_t)T_STEPS * BATCH * HDIM * 2);
  unsigned short* hxA   = (unsigned short*)alloc((size_t)BATCH * HDIM * 2);
  unsigned short* hxB   = (unsigned short*)alloc((size_t)BATCH * HDIM * 2);
  float* cx             = (float*)alloc((size_t)BATCH * HDIM * 4);
  int* bsz  = (int*)alloc(T_STEPS * 4);
  int* roff = (int*)alloc(T_STEPS * 4);
  int* meta = (int*)alloc(256);
  int* rmap = (int*)alloc(T_STEPS * BATCH * 4);

  k_prep<<<dim3(NB_CVTW + NB_WOUT + NB_XS + NB_CARRY + 1), 256, 0, stream>>>(
      W_ih, W_hh, W_out, img, txt, emb, answer, h0, c0, lengths,
      Wih_b, Whh_b, Wo_b, xs, hxA, cx, bsz, roff, meta, rmap);

  k_gemm_xw<<<dim3(T_STEPS * BATCH / 128, G4 / 128), 256, 0, stream>>>(xs, Wih_b, b_ih, b_hh, XW);

  unsigned short* hbuf[2] = { hxA, hxB };
  for (int t = 0; t < T_STEPS; t++){
    int do_res = (t >= 2 && (t % 3) == 0) ? 1 : 0;
    int tm2 = (t >= 2) ? (t - 2) : 0;
    k_lstm_step<<<dim3(BATCH / 16, HDIM / 16), 256, 0, stream>>>(
        XW + (size_t)t * BATCH * G4, Whh_b, hbuf[t & 1], hbuf[(t + 1) & 1], cx,
        hs + (size_t)t * BATCH * HDIM, cs + (size_t)t * BATCH * HDIM,
        hs + (size_t)tm2 * BATCH * HDIM, cs + (size_t)tm2 * BATCH * HDIM, do_res);
  }

  k_gemm_out<<<dim3(T_STEPS * BATCH / 128, VPAD / 128), 256, 0, stream>>>(hs, cs, Wo_b, b_out, meta, rmap, out);
}

// Round 17
// 337.398 us; speedup vs baseline: 1.0135x; 1.0135x over previous
//
#include <hip/hip_runtime.h>
#include <hip/hip_bf16.h>

#define T_STEPS 32
#define BATCH 256
#define EDIM 512
#define HDIM 512
#define G4 2048       // 4*H
#define VOCAB 3000
#define VPAD 3072

// fused-prep role ranges (blocks of 256 threads)
#define NB_CVTW   8192    // 2 * G4 * 512 / 256
#define NB_WOUT   12288   // VPAD * 1024 / 256
#define NB_XS     16384   // T * B * E / 256
#define NB_CARRY  512     // B * H / 256

typedef short bf16x8 __attribute__((ext_vector_type(8)));
typedef float f32x4 __attribute__((ext_vector_type(4)));

__device__ __forceinline__ unsigned short f2b(float f){
  union { float f; unsigned int u; } x; x.f = f;
  unsigned int u = x.u;
  unsigned int r = (u + 0x7fffu + ((u >> 16) & 1u)) >> 16;
  return (unsigned short)r;
}
__device__ __forceinline__ float b2f(unsigned short h){
  union { unsigned int u; float f; } x; x.u = ((unsigned int)h) << 16;
  return x.f;
}
__device__ __forceinline__ float sigm(float x){ return 1.0f / (1.0f + expf(-x)); }

__device__ __forceinline__ void gload_lds16(const unsigned short* g, unsigned short* l){
  __builtin_amdgcn_global_load_lds(
      (const __attribute__((address_space(1))) unsigned int*)g,
      (__attribute__((address_space(3))) unsigned int*)l, 16, 0, 0);
}

// ---------------- fused prep: all independent input->workspace transforms ----------------
__global__ __launch_bounds__(256) void k_prep(
    const float* __restrict__ wih, const float* __restrict__ whh,
    const float* __restrict__ wout,
    const float* __restrict__ img, const float* __restrict__ txt,
    const float* __restrict__ emb, const int* __restrict__ ans,
    const float* __restrict__ h0, const float* __restrict__ c0,
    const int* __restrict__ lengths,
    unsigned short* __restrict__ o_ih, unsigned short* __restrict__ o_hh,
    unsigned short* __restrict__ o_wo, unsigned short* __restrict__ xs,
    unsigned short* __restrict__ hx, float* __restrict__ cx,
    int* __restrict__ bs, int* __restrict__ roff, int* __restrict__ meta,
    int* __restrict__ rmap){
  int bid = blockIdx.x;
  if (bid < NB_CVTW){
    int i = bid * 256 + threadIdx.x;
    int n1 = G4 * EDIM;
    if (i < n1) o_ih[i] = f2b(wih[i]);
    else o_hh[i - n1] = f2b(whh[i - n1]);
    return;
  }
  bid -= NB_CVTW;
  if (bid < NB_WOUT){
    int i = bid * 256 + threadIdx.x;
    int r = i >> 10, c = i & 1023;
    o_wo[i] = (r < VOCAB) ? f2b(wout[r * 1024 + c]) : (unsigned short)0;
    return;
  }
  bid -= NB_WOUT;
  if (bid < NB_XS){
    int i = bid * 256 + threadIdx.x;
    int e = i & (EDIM - 1);
    int r = i >> 9;              // t*B + b
    int t = r >> 8, b = r & 255;
    float v;
    if (t == 0) v = (e < 256) ? img[b * 256 + e] : txt[b * 256 + (e - 256)];
    else { int tok = ans[b * T_STEPS + (t - 1)]; v = emb[(size_t)tok * EDIM + e]; }
    xs[i] = f2b(v);
    return;
  }
  bid -= NB_XS;
  if (bid < NB_CARRY){
    int i = bid * 256 + threadIdx.x;
    hx[i] = f2b(h0[i]); cx[i] = c0[i];
    return;
  }
  // ---- lens role: one block, 256 threads ----
  {
    __shared__ int s[T_STEPS];
    __shared__ int sroff[T_STEPS + 1];
    int t = threadIdx.x;
    if (t < T_STEPS){
      int c = 0;
      for (int i = 0; i < BATCH; i++) c += (lengths[i] > t) ? 1 : 0;
      s[t] = c; bs[t] = c;
    }
    __syncthreads();
    if (t == 0){
      int acc = 0;
      for (int u = 0; u < T_STEPS; u++){ sroff[u] = acc; roff[u] = acc; acc += s[u]; }
      sroff[T_STEPS] = acc;
      meta[0] = acc;
    }
    __syncthreads();
    int ntot = sroff[T_STEPS];
    for (int r = t; r < T_STEPS * BATCH; r += 256){
      int tt = r >> 8, b = r & 255;
      if (b < s[tt]) rmap[sroff[tt] + b] = r;
    }
    for (int r = ntot + t; r < T_STEPS * BATCH; r += 256) rmap[r] = -1;
  }
}

// ---------------- staged 128x128 GEMM core, BK=64, XOR-swizzled LDS ----------------
template<int K>
__device__ __forceinline__ void gemm_tile(const unsigned short* __restrict__ A,
                                          const unsigned short* __restrict__ B,
                                          int row0, int col0,
                                          unsigned short* As, unsigned short* Bs,
                                          f32x4 acc[4][4]){
  const int tid = threadIdx.x, w = tid >> 6, l = tid & 63;
  const int la = l & 15, lkq = l >> 4;
  const int sr = l >> 3;            // row within 8-row staging group
  const int ss = (l & 7) ^ sr;      // pre-swizzled source slot
  const int wr = (w >> 1) * 64, wc = (w & 1) * 64;
  const unsigned short* gA = A + (size_t)(row0 + w * 32 + sr) * K + ss * 8;
  const unsigned short* gB = B + (size_t)(col0 + w * 32 + sr) * K + ss * 8;
  unsigned short* lA = As + (w * 32) * 64;
  unsigned short* lB = Bs + (w * 32) * 64;
  for (int k0 = 0; k0 < K; k0 += 64){
#pragma unroll
    for (int i = 0; i < 4; i++){
      gload_lds16(gA + (size_t)i * 8 * K + k0, lA + i * 8 * 64);
      gload_lds16(gB + (size_t)i * 8 * K + k0, lB + i * 8 * 64);
    }
    __syncthreads();
#pragma unroll
    for (int kk = 0; kk < 2; kk++){
      bf16x8 a[4], b[4];
#pragma unroll
      for (int i = 0; i < 4; i++){
        int r = wr + i * 16 + la;
        a[i] = *(const bf16x8*)(As + r * 64 + (((kk * 4 + lkq) ^ (r & 7)) << 3));
      }
#pragma unroll
      for (int i = 0; i < 4; i++){
        int r = wc + i * 16 + la;
        b[i] = *(const bf16x8*)(Bs + r * 64 + (((kk * 4 + lkq) ^ (r & 7)) << 3));
      }
#pragma unroll
      for (int mi = 0; mi < 4; mi++)
#pragma unroll
        for (int ni = 0; ni < 4; ni++)
          acc[mi][ni] = __builtin_amdgcn_mfma_f32_16x16x32_bf16(a[mi], b[ni], acc[mi][ni], 0, 0, 0);
    }
    __syncthreads();
  }
}

// ---------------- GEMM 1: XW = xs @ W_ih^T + b_ih + b_hh (bf16 out) ----------------
__global__ __launch_bounds__(256) void k_gemm_xw(const unsigned short* __restrict__ A,
                                                 const unsigned short* __restrict__ W,
                                                 const float* __restrict__ bih,
                                                 const float* __restrict__ bhh,
                                                 unsigned short* __restrict__ C){
  __shared__ unsigned short As[128 * 64], Bs[128 * 64];
  int row0 = blockIdx.x * 128, col0 = blockIdx.y * 128;
  f32x4 acc[4][4] = {};
  gemm_tile<EDIM>(A, W, row0, col0, As, Bs, acc);
  int tid = threadIdx.x, w = tid >> 6, l = tid & 63;
  int la = l & 15, r4 = (l >> 4) * 4;
  int wr = (w >> 1) * 64, wc = (w & 1) * 64;
#pragma unroll
  for (int ni = 0; ni < 4; ni++){
    int col = col0 + wc + ni * 16 + la;
    float bias = bih[col] + bhh[col];
#pragma unroll
    for (int mi = 0; mi < 4; mi++)
#pragma unroll
      for (int j = 0; j < 4; j++){
        int row = row0 + wr + mi * 16 + r4 + j;
        C[(size_t)row * G4 + col] = f2b(acc[mi][ni][j] + bias);
      }
  }
}

// ---------------- fused recurrent step: 512 blocks (16 rows x 16 hcols), wave=gate ----
// All 16 Whh B-fragments hoisted into registers -> one batched latency exposure.
__global__ __launch_bounds__(256, 2) void k_lstm_step(
    const unsigned short* __restrict__ XWt,
    const unsigned short* __restrict__ Whh,
    const unsigned short* __restrict__ hin,
    unsigned short* __restrict__ hout,
    float* __restrict__ cxio,
    unsigned short* __restrict__ hs_t,
    unsigned short* __restrict__ cs_t,
    const unsigned short* __restrict__ hs_m2,
    const unsigned short* __restrict__ cs_m2,
    int do_res){
  __shared__ unsigned short hA[16 * 512];   // swizzled h tile
  __shared__ float gbuf[4][16][17];
  const int w = threadIdx.x >> 6, l = threadIdx.x & 63;
  const int la = l & 15, lkq = l >> 4;
  const int row0 = blockIdx.x * 16;
  const int hc0  = blockIdx.y * 16;
  // stage h tile: wave w stages rows {w, 4+w, 8+w, 12+w}; source slot pre-swizzled
#pragma unroll
  for (int i = 0; i < 4; i++){
    int r = i * 4 + w;
    gload_lds16(hin + (size_t)(row0 + r) * HDIM + ((l ^ (r & 7)) << 3), hA + r * 512);
  }
  // hoist ALL 16 Whh B-fragments (independent, issued back-to-back)
  const unsigned short* Bp = Whh + (size_t)(w * HDIM + hc0 + la) * HDIM + lkq * 8;
  bf16x8 b[16];
#pragma unroll
  for (int kk = 0; kk < 16; kk++) b[kk] = *(const bf16x8*)(Bp + kk * 32);
  // hoist XW (consumed after MFMA loop)
  const int r4 = lkq * 4;
  float x[4];
#pragma unroll
  for (int j = 0; j < 4; j++)
    x[j] = b2f(XWt[(size_t)(row0 + r4 + j) * G4 + w * HDIM + hc0 + la]);
  __syncthreads();
  f32x4 acc = {};
#pragma unroll
  for (int kk = 0; kk < 16; kk++){
    bf16x8 a = *(const bf16x8*)(hA + la * 512 + (((kk * 4 + lkq) ^ (la & 7)) << 3));
    acc = __builtin_amdgcn_mfma_f32_16x16x32_bf16(a, b[kk], acc, 0, 0, 0);
  }
#pragma unroll
  for (int j = 0; j < 4; j++) gbuf[w][r4 + j][la] = acc[j] + x[j];
  __syncthreads();
  {
    int r = threadIdx.x >> 4, c = threadIdx.x & 15;
    size_t p = (size_t)(row0 + r) * HDIM + hc0 + c;
    float gi = gbuf[0][r][c], gf = gbuf[1][r][c], gg = gbuf[2][r][c], go = gbuf[3][r][c];
    float cprev = cxio[p];
    float cy = sigm(gf) * cprev + sigm(gi) * tanhf(gg);
    float hy = sigm(go) * tanhf(cy);
    hs_t[p] = f2b(hy);
    cs_t[p] = f2b(cy);
    float hn = hy, cn = cy;
    if (do_res){ hn += b2f(hs_m2[p]); cn += b2f(cs_m2[p]); }
    hout[p] = f2b(hn);
    cxio[p] = cn;
  }
}

// ---------------- GEMM 2: packed output projection, A gathered via rmap ----------------
__global__ __launch_bounds__(256) void k_gemm_out(const unsigned short* __restrict__ hs,
                                                  const unsigned short* __restrict__ cs,
                                                  const unsigned short* __restrict__ Wo,
                                                  const float* __restrict__ bout,
                                                  const int* __restrict__ meta,
                                                  const int* __restrict__ rmap,
                                                  float* __restrict__ out){
  int ntot = meta[0];
  int row0 = blockIdx.x * 128, col0 = blockIdx.y * 128;
  if (row0 >= ntot) return;
  __shared__ unsigned short As[128 * 64], Bs[128 * 64];
  const int tid = threadIdx.x, w = tid >> 6, l = tid & 63;
  const int la = l & 15, lkq = l >> 4;
  const int sr = l >> 3, ss = (l & 7) ^ sr;
  const int wr = (w >> 1) * 64, wc = (w & 1) * 64;
  int srow[4];
#pragma unroll
  for (int i = 0; i < 4; i++){
    int rr = rmap[row0 + w * 32 + sr + i * 8];
    srow[i] = rr < 0 ? 0 : rr;
  }
  const unsigned short* gB = Wo + (size_t)(col0 + w * 32 + sr) * 1024 + ss * 8;
  unsigned short* lA = As + (w * 32) * 64;
  unsigned short* lB = Bs + (w * 32) * 64;
  f32x4 acc[4][4] = {};
  for (int k0 = 0; k0 < 1024; k0 += 64){
#pragma unroll
    for (int i = 0; i < 4; i++){
      const unsigned short* srcA = (k0 < 512)
          ? hs + (size_t)srow[i] * 512 + k0 + ss * 8
          : cs + (size_t)srow[i] * 512 + (k0 - 512) + ss * 8;
      gload_lds16(srcA, lA + i * 8 * 64);
      gload_lds16(gB + (size_t)i * 8 * 1024 + k0, lB + i * 8 * 64);
    }
    __syncthreads();
#pragma unroll
    for (int kk = 0; kk < 2; kk++){
      bf16x8 a[4], b[4];
#pragma unroll
      for (int i = 0; i < 4; i++){
        int r = wr + i * 16 + la;
        a[i] = *(const bf16x8*)(As + r * 64 + (((kk * 4 + lkq) ^ (r & 7)) << 3));
      }
#pragma unroll
      for (int i = 0; i < 4; i++){
        int r = wc + i * 16 + la;
        b[i] = *(const bf16x8*)(Bs + r * 64 + (((kk * 4 + lkq) ^ (r & 7)) << 3));
      }
#pragma unroll
      for (int mi = 0; mi < 4; mi++)
#pragma unroll
        for (int ni = 0; ni < 4; ni++)
          acc[mi][ni] = __builtin_amdgcn_mfma_f32_16x16x32_bf16(a[mi], b[ni], acc[mi][ni], 0, 0, 0);
    }
    __syncthreads();
  }
  int r4 = (l >> 4) * 4;
#pragma unroll
  for (int ni = 0; ni < 4; ni++){
    int col = col0 + wc + ni * 16 + la;
    if (col >= VOCAB) continue;
    float bias = bout[col];
#pragma unroll
    for (int mi = 0; mi < 4; mi++)
#pragma unroll
      for (int j = 0; j < 4; j++){
        int row = row0 + wr + mi * 16 + r4 + j;
        if (row < ntot) out[(size_t)row * VOCAB + col] = acc[mi][ni][j] + bias;
      }
  }
}

extern "C" void kernel_launch(void* const* d_in, const int* in_sizes, int n_in,
                              void* d_out, int out_size, void* d_ws, size_t ws_size,
                              hipStream_t stream){
  const float* img   = (const float*)d_in[0];
  const float* txt   = (const float*)d_in[1];
  const float* h0    = (const float*)d_in[2];
  const float* c0    = (const float*)d_in[3];
  const float* emb   = (const float*)d_in[4];
  const float* W_ih  = (const float*)d_in[5];
  const float* W_hh  = (const float*)d_in[6];
  const float* b_ih  = (const float*)d_in[7];
  const float* b_hh  = (const float*)d_in[8];
  const float* W_out = (const float*)d_in[9];
  const float* b_out = (const float*)d_in[10];
  const int* answer  = (const int*)d_in[11];
  const int* lengths = (const int*)d_in[12];
  float* out = (float*)d_out;

  char* ws = (char*)d_ws;
  size_t off = 0;
  auto alloc = [&](size_t bytes) -> void* {
    void* p = ws + off; off += (bytes + 255) & ~(size_t)255; return p;
  };
  unsigned short* Wih_b = (unsigned short*)alloc((size_t)G4 * EDIM * 2);
  unsigned short* Whh_b = (unsigned short*)alloc((size_t)G4 * HDIM * 2);
  unsigned short* Wo_b  = (unsigned short*)alloc((size_t)VPAD * 1024 * 2);
  unsigned short* xs    = (unsigned short*)alloc((size_t)T_STEPS * BATCH * EDIM * 2);
  unsigned short* XW    = (unsigned short*)alloc((size_t)T_STEPS * BATCH * G4 * 2);
  unsigned short* hs    = (unsigned short*)alloc((size_t)T_STEPS * BATCH * HDIM * 2);
  unsigned short* cs    = (unsigned short*)alloc((size_t)T_STEPS * BATCH * HDIM * 2);
  unsigned short* hxA   = (unsigned short*)alloc((size_t)BATCH * HDIM * 2);
  unsigned short* hxB   = (unsigned short*)alloc((size_t)BATCH * HDIM * 2);
  float* cx             = (float*)alloc((size_t)BATCH * HDIM * 4);
  int* bsz  = (int*)alloc(T_STEPS * 4);
  int* roff = (int*)alloc(T_STEPS * 4);
  int* meta = (int*)alloc(256);
  int* rmap = (int*)alloc(T_STEPS * BATCH * 4);

  k_prep<<<dim3(NB_CVTW + NB_WOUT + NB_XS + NB_CARRY + 1), 256, 0, stream>>>(
      W_ih, W_hh, W_out, img, txt, emb, answer, h0, c0, lengths,
      Wih_b, Whh_b, Wo_b, xs, hxA, cx, bsz, roff, meta, rmap);

  k_gemm_xw<<<dim3(T_STEPS * BATCH / 128, G4 / 128), 256, 0, stream>>>(xs, Wih_b, b_ih, b_hh, XW);

  unsigned short* hbuf[2] = { hxA, hxB };
  for (int t = 0; t < T_STEPS; t++){
    int do_res = (t >= 2 && (t % 3) == 0) ? 1 : 0;
    int tm2 = (t >= 2) ? (t - 2) : 0;
    k_lstm_step<<<dim3(BATCH / 16, HDIM / 16), 256, 0, stream>>>(
        XW + (size_t)t * BATCH * G4, Whh_b, hbuf[t & 1], hbuf[(t + 1) & 1], cx,
        hs + (size_t)t * BATCH * HDIM, cs + (size_t)t * BATCH * HDIM,
        hs + (size_t)tm2 * BATCH * HDIM, cs + (size_t)tm2 * BATCH * HDIM, do_res);
  }

  k_gemm_out<<<dim3(T_STEPS * BATCH / 128, VPAD / 128), 256, 0, stream>>>(hs, cs, Wo_b, b_out, meta, rmap, out);
}

// Round 18
// 330.021 us; speedup vs baseline: 1.0361x; 1.0224x over previous
//
#include <hip/hip_runtime.h>
#include <hip/hip_bf16.h>

#define T_STEPS 32
#define BATCH 256
#define EDIM 512
#define HDIM 512
#define G4 2048       // 4*H
#define VOCAB 3000
#define VPAD 3072

// fused-prep role ranges (blocks of 256 threads)
#define NB_CVTW   8192    // 2 * G4 * 512 / 256
#define NB_WOUT   12288   // VPAD * 1024 / 256
#define NB_XS     16384   // T * B * E / 256
#define NB_CARRY  512     // B * H / 256

typedef short bf16x8 __attribute__((ext_vector_type(8)));
typedef float f32x4 __attribute__((ext_vector_type(4)));

__device__ __forceinline__ unsigned short f2b(float f){
  union { float f; unsigned int u; } x; x.f = f;
  unsigned int u = x.u;
  unsigned int r = (u + 0x7fffu + ((u >> 16) & 1u)) >> 16;
  return (unsigned short)r;
}
__device__ __forceinline__ float b2f(unsigned short h){
  union { unsigned int u; float f; } x; x.u = ((unsigned int)h) << 16;
  return x.f;
}
__device__ __forceinline__ float sigm(float x){ return 1.0f / (1.0f + expf(-x)); }

__device__ __forceinline__ void gload_lds16(const unsigned short* g, unsigned short* l){
  __builtin_amdgcn_global_load_lds(
      (const __attribute__((address_space(1))) unsigned int*)g,
      (__attribute__((address_space(3))) unsigned int*)l, 16, 0, 0);
}

// ---------------- fused prep: all independent input->workspace transforms ----------------
__global__ __launch_bounds__(256) void k_prep(
    const float* __restrict__ wih, const float* __restrict__ whh,
    const float* __restrict__ wout,
    const float* __restrict__ img, const float* __restrict__ txt,
    const float* __restrict__ emb, const int* __restrict__ ans,
    const float* __restrict__ h0, const float* __restrict__ c0,
    const int* __restrict__ lengths,
    unsigned short* __restrict__ o_ih, unsigned short* __restrict__ o_hh,
    unsigned short* __restrict__ o_wo, unsigned short* __restrict__ xs,
    unsigned short* __restrict__ hx, float* __restrict__ cx,
    int* __restrict__ bs, int* __restrict__ roff, int* __restrict__ meta){
  int bid = blockIdx.x;
  if (bid < NB_CVTW){
    int i = bid * 256 + threadIdx.x;
    int n1 = G4 * EDIM;
    if (i < n1) o_ih[i] = f2b(wih[i]);
    else o_hh[i - n1] = f2b(whh[i - n1]);
    return;
  }
  bid -= NB_CVTW;
  if (bid < NB_WOUT){
    int i = bid * 256 + threadIdx.x;
    int r = i >> 10, c = i & 1023;
    o_wo[i] = (r < VOCAB) ? f2b(wout[r * 1024 + c]) : (unsigned short)0;
    return;
  }
  bid -= NB_WOUT;
  if (bid < NB_XS){
    int i = bid * 256 + threadIdx.x;
    int e = i & (EDIM - 1);
    int r = i >> 9;              // t*B + b
    int t = r >> 8, b = r & 255;
    float v;
    if (t == 0) v = (e < 256) ? img[b * 256 + e] : txt[b * 256 + (e - 256)];
    else { int tok = ans[b * T_STEPS + (t - 1)]; v = emb[(size_t)tok * EDIM + e]; }
    xs[i] = f2b(v);
    return;
  }
  bid -= NB_XS;
  if (bid < NB_CARRY){
    int i = bid * 256 + threadIdx.x;
    hx[i] = f2b(h0[i]); cx[i] = c0[i];
    return;
  }
  // ---- lens role: one block, 256 threads ----
  {
    __shared__ int s[T_STEPS];
    int t = threadIdx.x;
    if (t < T_STEPS){
      int c = 0;
      for (int i = 0; i < BATCH; i++) c += (lengths[i] > t) ? 1 : 0;
      s[t] = c; bs[t] = c;
    }
    __syncthreads();
    if (t == 0){
      int acc = 0;
      for (int u = 0; u < T_STEPS; u++){ roff[u] = acc; acc += s[u]; }
      meta[0] = acc;
    }
  }
}

// ---------------- staged 128x128 GEMM core, BK=64, XOR-swizzled LDS ----------------
template<int K>
__device__ __forceinline__ void gemm_tile(const unsigned short* __restrict__ A,
                                          const unsigned short* __restrict__ B,
                                          int row0, int col0,
                                          unsigned short* As, unsigned short* Bs,
                                          f32x4 acc[4][4]){
  const int tid = threadIdx.x, w = tid >> 6, l = tid & 63;
  const int la = l & 15, lkq = l >> 4;
  const int sr = l >> 3;            // row within 8-row staging group
  const int ss = (l & 7) ^ sr;      // pre-swizzled source slot
  const int wr = (w >> 1) * 64, wc = (w & 1) * 64;
  const unsigned short* gA = A + (size_t)(row0 + w * 32 + sr) * K + ss * 8;
  const unsigned short* gB = B + (size_t)(col0 + w * 32 + sr) * K + ss * 8;
  unsigned short* lA = As + (w * 32) * 64;
  unsigned short* lB = Bs + (w * 32) * 64;
  for (int k0 = 0; k0 < K; k0 += 64){
#pragma unroll
    for (int i = 0; i < 4; i++){
      gload_lds16(gA + (size_t)i * 8 * K + k0, lA + i * 8 * 64);
      gload_lds16(gB + (size_t)i * 8 * K + k0, lB + i * 8 * 64);
    }
    __syncthreads();
#pragma unroll
    for (int kk = 0; kk < 2; kk++){
      bf16x8 a[4], b[4];
#pragma unroll
      for (int i = 0; i < 4; i++){
        int r = wr + i * 16 + la;
        a[i] = *(const bf16x8*)(As + r * 64 + (((kk * 4 + lkq) ^ (r & 7)) << 3));
      }
#pragma unroll
      for (int i = 0; i < 4; i++){
        int r = wc + i * 16 + la;
        b[i] = *(const bf16x8*)(Bs + r * 64 + (((kk * 4 + lkq) ^ (r & 7)) << 3));
      }
#pragma unroll
      for (int mi = 0; mi < 4; mi++)
#pragma unroll
        for (int ni = 0; ni < 4; ni++)
          acc[mi][ni] = __builtin_amdgcn_mfma_f32_16x16x32_bf16(a[mi], b[ni], acc[mi][ni], 0, 0, 0);
    }
    __syncthreads();
  }
}

// ---------------- GEMM 1: XW = xs @ W_ih^T + b_ih + b_hh (bf16 out) ----------------
__global__ __launch_bounds__(256) void k_gemm_xw(const unsigned short* __restrict__ A,
                                                 const unsigned short* __restrict__ W,
                                                 const float* __restrict__ bih,
                                                 const float* __restrict__ bhh,
                                                 unsigned short* __restrict__ C){
  __shared__ unsigned short As[128 * 64], Bs[128 * 64];
  int row0 = blockIdx.x * 128, col0 = blockIdx.y * 128;
  f32x4 acc[4][4] = {};
  gemm_tile<EDIM>(A, W, row0, col0, As, Bs, acc);
  int tid = threadIdx.x, w = tid >> 6, l = tid & 63;
  int la = l & 15, r4 = (l >> 4) * 4;
  int wr = (w >> 1) * 64, wc = (w & 1) * 64;
#pragma unroll
  for (int ni = 0; ni < 4; ni++){
    int col = col0 + wc + ni * 16 + la;
    float bias = bih[col] + bhh[col];
#pragma unroll
    for (int mi = 0; mi < 4; mi++)
#pragma unroll
      for (int j = 0; j < 4; j++){
        int row = row0 + wr + mi * 16 + r4 + j;
        C[(size_t)row * G4 + col] = f2b(acc[mi][ni][j] + bias);
      }
  }
}

// ---------------- fused recurrent step: 512 blocks (16 rows x 16 hcols), wave=gate ----
// b[16] Whh hoist (r7) + NEW: cell phase also writes the packed output-GEMM A-row
// (Apack[roff[t]+b][h | 512+h]) so gemm_out reads a dense contiguous A (no rmap gather).
__global__ __launch_bounds__(256, 2) void k_lstm_step(
    const unsigned short* __restrict__ XWt,
    const unsigned short* __restrict__ Whh,
    const unsigned short* __restrict__ hin,
    unsigned short* __restrict__ hout,
    float* __restrict__ cxio,
    unsigned short* __restrict__ hs_t,
    unsigned short* __restrict__ cs_t,
    const unsigned short* __restrict__ hs_m2,
    const unsigned short* __restrict__ cs_m2,
    int do_res,
    const int* __restrict__ bsp,
    const int* __restrict__ roffp,
    int t,
    unsigned short* __restrict__ Apack){
  __shared__ unsigned short hA[16 * 512];   // swizzled h tile
  __shared__ float gbuf[4][16][17];
  const int w = threadIdx.x >> 6, l = threadIdx.x & 63;
  const int la = l & 15, lkq = l >> 4;
  const int row0 = blockIdx.x * 16;
  const int hc0  = blockIdx.y * 16;
  // uniform packed-row metadata (issued early, consumed in cell phase)
  const int bs_t = bsp[t];
  const int roff_t = roffp[t];
  // stage h tile: wave w stages rows {w, 4+w, 8+w, 12+w}; source slot pre-swizzled
#pragma unroll
  for (int i = 0; i < 4; i++){
    int r = i * 4 + w;
    gload_lds16(hin + (size_t)(row0 + r) * HDIM + ((l ^ (r & 7)) << 3), hA + r * 512);
  }
  // hoist ALL 16 Whh B-fragments (independent, issued back-to-back)
  const unsigned short* Bp = Whh + (size_t)(w * HDIM + hc0 + la) * HDIM + lkq * 8;
  bf16x8 b[16];
#pragma unroll
  for (int kk = 0; kk < 16; kk++) b[kk] = *(const bf16x8*)(Bp + kk * 32);
  // hoist XW (consumed after MFMA loop)
  const int r4 = lkq * 4;
  float x[4];
#pragma unroll
  for (int j = 0; j < 4; j++)
    x[j] = b2f(XWt[(size_t)(row0 + r4 + j) * G4 + w * HDIM + hc0 + la]);
  __syncthreads();
  f32x4 acc = {};
#pragma unroll
  for (int kk = 0; kk < 16; kk++){
    bf16x8 a = *(const bf16x8*)(hA + la * 512 + (((kk * 4 + lkq) ^ (la & 7)) << 3));
    acc = __builtin_amdgcn_mfma_f32_16x16x32_bf16(a, b[kk], acc, 0, 0, 0);
  }
#pragma unroll
  for (int j = 0; j < 4; j++) gbuf[w][r4 + j][la] = acc[j] + x[j];
  __syncthreads();
  {
    int r = threadIdx.x >> 4, c = threadIdx.x & 15;
    size_t p = (size_t)(row0 + r) * HDIM + hc0 + c;
    float gi = gbuf[0][r][c], gf = gbuf[1][r][c], gg = gbuf[2][r][c], go = gbuf[3][r][c];
    float cprev = cxio[p];
    float cy = sigm(gf) * cprev + sigm(gi) * tanhf(gg);
    float hy = sigm(go) * tanhf(cy);
    unsigned short hyb = f2b(hy), cyb = f2b(cy);
    hs_t[p] = hyb;
    cs_t[p] = cyb;
    // dense packed A-row for the output GEMM (valid rows only)
    if (row0 + r < bs_t){
      size_t pa = (size_t)(roff_t + row0 + r) * 1024 + hc0 + c;
      Apack[pa] = hyb;
      Apack[pa + 512] = cyb;
    }
    float hn = hy, cn = cy;
    if (do_res){ hn += b2f(hs_m2[p]); cn += b2f(cs_m2[p]); }
    hout[p] = f2b(hn);
    cxio[p] = cn;
  }
}

// ---------------- GEMM 2: packed output projection over dense Apack ----------------
__global__ __launch_bounds__(256) void k_gemm_out(const unsigned short* __restrict__ Ap,
                                                  const unsigned short* __restrict__ Wo,
                                                  const float* __restrict__ bout,
                                                  const int* __restrict__ meta,
                                                  float* __restrict__ out){
  int ntot = meta[0];
  int row0 = blockIdx.x * 128, col0 = blockIdx.y * 128;
  if (row0 >= ntot) return;
  __shared__ unsigned short As[128 * 64], Bs[128 * 64];
  f32x4 acc[4][4] = {};
  gemm_tile<1024>(Ap, Wo, row0, col0, As, Bs, acc);
  int tid = threadIdx.x, w = tid >> 6, l = tid & 63;
  int la = l & 15, r4 = (l >> 4) * 4;
  int wr = (w >> 1) * 64, wc = (w & 1) * 64;
#pragma unroll
  for (int ni = 0; ni < 4; ni++){
    int col = col0 + wc + ni * 16 + la;
    if (col >= VOCAB) continue;
    float bias = bout[col];
#pragma unroll
    for (int mi = 0; mi < 4; mi++)
#pragma unroll
      for (int j = 0; j < 4; j++){
        int row = row0 + wr + mi * 16 + r4 + j;
        if (row < ntot) out[(size_t)row * VOCAB + col] = acc[mi][ni][j] + bias;
      }
  }
}

extern "C" void kernel_launch(void* const* d_in, const int* in_sizes, int n_in,
                              void* d_out, int out_size, void* d_ws, size_t ws_size,
                              hipStream_t stream){
  const float* img   = (const float*)d_in[0];
  const float* txt   = (const float*)d_in[1];
  const float* h0    = (const float*)d_in[2];
  const float* c0    = (const float*)d_in[3];
  const float* emb   = (const float*)d_in[4];
  const float* W_ih  = (const float*)d_in[5];
  const float* W_hh  = (const float*)d_in[6];
  const float* b_ih  = (const float*)d_in[7];
  const float* b_hh  = (const float*)d_in[8];
  const float* W_out = (const float*)d_in[9];
  const float* b_out = (const float*)d_in[10];
  const int* answer  = (const int*)d_in[11];
  const int* lengths = (const int*)d_in[12];
  float* out = (float*)d_out;

  char* ws = (char*)d_ws;
  size_t off = 0;
  auto alloc = [&](size_t bytes) -> void* {
    void* p = ws + off; off += (bytes + 255) & ~(size_t)255; return p;
  };
  unsigned short* Wih_b = (unsigned short*)alloc((size_t)G4 * EDIM * 2);
  unsigned short* Whh_b = (unsigned short*)alloc((size_t)G4 * HDIM * 2);
  unsigned short* Wo_b  = (unsigned short*)alloc((size_t)VPAD * 1024 * 2);
  unsigned short* xs    = (unsigned short*)alloc((size_t)T_STEPS * BATCH * EDIM * 2);
  unsigned short* XW    = (unsigned short*)alloc((size_t)T_STEPS * BATCH * G4 * 2);
  unsigned short* hs    = (unsigned short*)alloc((size_t)T_STEPS * BATCH * HDIM * 2);
  unsigned short* cs    = (unsigned short*)alloc((size_t)T_STEPS * BATCH * HDIM * 2);
  unsigned short* Apack = (unsigned short*)alloc((size_t)T_STEPS * BATCH * 1024 * 2);
  unsigned short* hxA   = (unsigned short*)alloc((size_t)BATCH * HDIM * 2);
  unsigned short* hxB   = (unsigned short*)alloc((size_t)BATCH * HDIM * 2);
  float* cx             = (float*)alloc((size_t)BATCH * HDIM * 4);
  int* bsz  = (int*)alloc(T_STEPS * 4);
  int* roff = (int*)alloc(T_STEPS * 4);
  int* meta = (int*)alloc(256);

  k_prep<<<dim3(NB_CVTW + NB_WOUT + NB_XS + NB_CARRY + 1), 256, 0, stream>>>(
      W_ih, W_hh, W_out, img, txt, emb, answer, h0, c0, lengths,
      Wih_b, Whh_b, Wo_b, xs, hxA, cx, bsz, roff, meta);

  k_gemm_xw<<<dim3(T_STEPS * BATCH / 128, G4 / 128), 256, 0, stream>>>(xs, Wih_b, b_ih, b_hh, XW);

  unsigned short* hbuf[2] = { hxA, hxB };
  for (int t = 0; t < T_STEPS; t++){
    int do_res = (t >= 2 && (t % 3) == 0) ? 1 : 0;
    int tm2 = (t >= 2) ? (t - 2) : 0;
    k_lstm_step<<<dim3(BATCH / 16, HDIM / 16), 256, 0, stream>>>(
        XW + (size_t)t * BATCH * G4, Whh_b, hbuf[t & 1], hbuf[(t + 1) & 1], cx,
        hs + (size_t)t * BATCH * HDIM, cs + (size_t)t * BATCH * HDIM,
        hs + (size_t)tm2 * BATCH * HDIM, cs + (size_t)tm2 * BATCH * HDIM, do_res,
        bsz, roff, t, Apack);
  }

  k_gemm_out<<<dim3(T_STEPS * BATCH / 128, VPAD / 128), 256, 0, stream>>>(Apack, Wo_b, b_out, meta, out);
}